// Round 1
// 83.149 us; speedup vs baseline: 1.1717x; 1.1717x over previous
//
#include <hip/hip_runtime.h>
#include <hip/hip_bf16.h>

// ---------------------------------------------------------------------------
// ContrastiveLoss: B=8192, D=64, fp32 inputs, scalar fp32 output.
// loss = mean_i[ w_i * (-(d_i - lse_row_i) - (d_i - lse_col_i)) ] / 2
//   w_i = (1 - exp(d_i - lse_row_i))^2,  d_i = (img_i . txt_i)/T (fp32 exact)
//   lse_row_i = M + ln( sum_j exp(s_ij - M) ),  M = 1/T  (fixed shift: |s|<=M
//   since both factors are unit vectors -> no max pass needed)
// Trick: imgB rows are pre-scaled by K1 = LOG2E/T and the MFMA C-operand is
// initialized to -K1, so the accumulator exits the matrix pipe as the exp2
// argument directly: acc = K1*dot - K1 = (s - M)*log2(e). Zero VALU fixup.
// This revision: rowPart/colPart partial ARRAYS (5 MB write + 5 MB read)
// replaced by device-scope fp32 atomics into rowSum/colSum[8192]; score's
// row flush rewritten as a 4-stage butterfly reduce-scatter (15 shuffles
// instead of 64) ending in one full-wave 64-lane atomic; norm vectorized
// (float4 loads, 4 rows/wave). finish now reads 96 KB instead of 5 MB.
// ---------------------------------------------------------------------------

#define NB 8192
#define ND 64

constexpr float INV_T = 1.0f / 0.07f;                 // 14.2857...
constexpr float LOG2E = 1.4426950408889634f;
constexpr float LN2   = 0.6931471805599453f;
constexpr float K1    = INV_T * LOG2E;                // exp2 arg scale

typedef float  floatx4 __attribute__((ext_vector_type(4)));
typedef short  bf16x8  __attribute__((ext_vector_type(8)));
typedef short  shortx4 __attribute__((ext_vector_type(4)));

// --------------------------- kernel 1: normalize ---------------------------
// 512 blocks x 256 threads. Each wave handles 4 rows: 16 lanes per row, one
// float4 per lane (coalesced dwordx4). Fused 4-step butterfly reduces
// |x|^2, |t|^2, x.t together within each 16-lane group. imgB gets the
// K1-prescaled bf16 copy (A side), txtB the plain normalized bf16 (B side).
// Also zeroes out[0] and the rowSum/colSum accumulators (workspace is
// poisoned each iteration, and score accumulates into them atomically).
__global__ __launch_bounds__(256)
void norm_kernel(const float* __restrict__ img, const float* __restrict__ txt,
                 __hip_bfloat16* __restrict__ imgB,
                 __hip_bfloat16* __restrict__ txtB,
                 float* __restrict__ diag,
                 float* __restrict__ rowSum,
                 float* __restrict__ colSum,
                 float* __restrict__ out)
{
    const int tid = blockIdx.x * 256 + threadIdx.x;
    if (tid < NB) { rowSum[tid] = 0.f; colSum[tid] = 0.f; }   // blocks 0..31
    if (tid == 0) out[0] = 0.f;                               // replaces memset

    const int lane = threadIdx.x & 63;
    const int gw   = blockIdx.x * 4 + (threadIdx.x >> 6);     // 0..2047
    const int sub  = lane >> 4;                               // row within wave
    const int c16  = lane & 15;                               // float4 slot
    const int row  = gw * 4 + sub;                            // 0..8191

    const floatx4 x = ((const floatx4*)img)[row * 16 + c16];
    const floatx4 t = ((const floatx4*)txt)[row * 16 + c16];
    float sx  = x[0]*x[0] + x[1]*x[1] + x[2]*x[2] + x[3]*x[3];
    float st  = t[0]*t[0] + t[1]*t[1] + t[2]*t[2] + t[3]*t[3];
    float sxt = x[0]*t[0] + x[1]*t[1] + x[2]*t[2] + x[3]*t[3];
    #pragma unroll
    for (int o = 1; o < 16; o <<= 1) {
        sx  += __shfl_xor(sx,  o, 64);
        st  += __shfl_xor(st,  o, 64);
        sxt += __shfl_xor(sxt, o, 64);
    }
    const float nx = fmaxf(sqrtf(sx), 1e-12f);
    const float nt = fmaxf(sqrtf(st), 1e-12f);
    shortx4 xb, tb;
    #pragma unroll
    for (int j = 0; j < 4; ++j) {
        __hip_bfloat16 hx = __float2bfloat16(x[j] / nx * K1);  // A pre-scaled
        __hip_bfloat16 ht = __float2bfloat16(t[j] / nt);
        xb[j] = *reinterpret_cast<const short*>(&hx);
        tb[j] = *reinterpret_cast<const short*>(&ht);
    }
    ((shortx4*)imgB)[row * 16 + c16] = xb;                    // 8B coalesced
    ((shortx4*)txtB)[row * 16 + c16] = tb;
    if (c16 == 0) diag[row] = sxt / (nx * nt) * INV_T;        // exact fp32 diag
}

// ----------------------- kernel 2: streamed score pass ---------------------
// Wave w: strip = w>>5 (64 rows), chunk = w&31 (256 cols, 16 tiles of 16).
// A-fragments (4 row-tiles) stay in registers across the whole tile loop.
// Next tile's B-fragments are software-prefetched (branchless wraparound).
// Per 16x16 tile: 2 chained MFMAs (K=64, C init = -K1) x 4 row-tiles,
// 16 exp2 straight off the accumulator, row partials in registers,
// col partial via depth-4 tree + 2 shuffles -> 16-lane atomic to colSum.
// Row partials: butterfly reduce-scatter (d=8,4,2,1; 15 shuffles, 15 adds)
// leaves lane (m,q) holding the full 256-col partial of row
// rowbase + (m>>2)*16 + q*4 + (m&3) -> ONE 64-lane atomic covers the strip.
// mfma_f32_16x16x32_bf16 layouts (HW-verified):
//   A: lane holds A[m=lane&15][k=(lane>>4)*8 + j], j=0..7  (8 contig bf16)
//   B: lane holds B[n=lane&15][k=(lane>>4)*8 + j]          (NT layout)
//   C/D: col = lane&15, row = (lane>>4)*4 + r
__global__ __launch_bounds__(256)
void score_kernel(const __hip_bfloat16* __restrict__ imgB,
                  const __hip_bfloat16* __restrict__ txtB,
                  float* __restrict__ rowSum,    // [8192] atomic accum
                  float* __restrict__ colSum)    // [8192] atomic accum
{
    const int wid   = threadIdx.x >> 6;
    const int lane  = threadIdx.x & 63;
    const int gw    = blockIdx.x * 4 + wid;   // 0..4095
    const int strip = gw >> 5;                // rows strip*64..+63
    const int chunk = gw & 31;                // cols chunk*256..+255
    const int m = lane & 15;
    const int q = lane >> 4;

    const bf16x8* __restrict__ A  = (const bf16x8*)imgB;  // units of 8 elems
    const bf16x8* __restrict__ Bp = (const bf16x8*)txtB;

    const int rowbase = strip * 64;
    bf16x8 a[4][2];
    #pragma unroll
    for (int it = 0; it < 4; ++it) {
        const int r = rowbase + it * 16 + m;
        a[it][0] = A[r * 8 + q];        // k = q*8 .. q*8+7
        a[it][1] = A[r * 8 + 4 + q];    // k = 32 + q*8 ..
    }

    const int colbase = chunk * 256 + m;      // this lane's t=0 column
    bf16x8 b0 = Bp[colbase * 8 + q];
    bf16x8 b1 = Bp[colbase * 8 + 4 + q];

    float rs[16];
    #pragma unroll
    for (int i = 0; i < 16; ++i) rs[i] = 0.f;

    const floatx4 NEGK = {-K1, -K1, -K1, -K1};   // bakes the -M shift in

    #pragma unroll 2
    for (int t = 0; t < 16; ++t) {
        // prefetch next tile's B (t=15 wraps to t=0: harmless, avoids branch)
        const int nn = colbase + (((t + 1) & 15) << 4);
        const bf16x8 pb0 = Bp[nn * 8 + q];
        const bf16x8 pb1 = Bp[nn * 8 + 4 + q];

        float csp[4];
        #pragma unroll
        for (int it = 0; it < 4; ++it) {
            floatx4 z   = __builtin_amdgcn_mfma_f32_16x16x32_bf16(a[it][0], b0, NEGK, 0, 0, 0);
            floatx4 acc = __builtin_amdgcn_mfma_f32_16x16x32_bf16(a[it][1], b1, z,    0, 0, 0);
            // acc == (s - M) * log2(e) already
            const float e0 = __builtin_amdgcn_exp2f(acc[0]);
            const float e1 = __builtin_amdgcn_exp2f(acc[1]);
            const float e2 = __builtin_amdgcn_exp2f(acc[2]);
            const float e3 = __builtin_amdgcn_exp2f(acc[3]);
            rs[it * 4 + 0] += e0;
            rs[it * 4 + 1] += e1;
            rs[it * 4 + 2] += e2;
            rs[it * 4 + 3] += e3;
            csp[it] = (e0 + e1) + (e2 + e3);     // depth-2 tree
        }
        float cs = (csp[0] + csp[1]) + (csp[2] + csp[3]);
        // combine the 4 quads -> col sum over all 64 rows of the strip
        cs += __shfl_xor(cs, 16, 64);
        cs += __shfl_xor(cs, 32, 64);
        if (q == 0)
            unsafeAtomicAdd(&colSum[colbase + (t << 4)], cs);  // 16 lanes, HW f32 atomic
        b0 = pb0; b1 = pb1;
    }

    // Butterfly reduce-scatter over the 16 m-lanes (per q-group):
    // after stage d, lanes whose bit log2(d) of m is set own the upper-half
    // indices. Final: lane m holds the full strip-row sum for idx == m.
#define RS_STAGE(d)                                                     \
    {                                                                   \
        const bool hi = (m & (d)) != 0;                                 \
        _Pragma("unroll")                                               \
        for (int j = 0; j < (d); ++j) {                                 \
            const float va = rs[j], vb = rs[j + (d)];                   \
            const float send = hi ? va : vb;                            \
            const float recv = __shfl_xor(send, (d), 64);               \
            rs[j] = (hi ? vb : va) + recv;                              \
        }                                                               \
    }
    RS_STAGE(8)
    RS_STAGE(4)
    RS_STAGE(2)
    RS_STAGE(1)
#undef RS_STAGE

    // idx == m: it = m>>2, r = m&3; all 64 lanes hit 64 distinct rows
    const int row = rowbase + ((m >> 2) << 4) + (q << 2) + (m & 3);
    unsafeAtomicAdd(&rowSum[row], rs[0]);
}

// --------------------------- kernel 3: finish ------------------------------
// Now reads only 96 KB (rowSum + colSum + diag) instead of 5 MB of partials.
__global__ __launch_bounds__(256)
void finish_kernel(const float* __restrict__ rowSum,
                   const float* __restrict__ colSum,
                   const float* __restrict__ diag,
                   float* __restrict__ out)
{
    const int i = blockIdx.x * 256 + threadIdx.x;   // 0..8191
    const float rowS = rowSum[i];
    const float colS = colSum[i];
    const float d     = diag[i];
    const float lse_r = INV_T + __builtin_amdgcn_logf(rowS) * LN2;
    const float lse_c = INV_T + __builtin_amdgcn_logf(colS) * LN2;
    const float lpr = d - lse_r;
    const float lpc = d - lse_c;
    const float p   = __builtin_amdgcn_exp2f(lpr * LOG2E);
    const float om  = 1.f - p;
    float contrib = om * om * (-lpr - lpc) * (0.5f / (float)NB);

    #pragma unroll
    for (int o = 1; o < 64; o <<= 1) contrib += __shfl_xor(contrib, o, 64);
    __shared__ float red[4];
    if ((threadIdx.x & 63) == 0) red[threadIdx.x >> 6] = contrib;
    __syncthreads();
    if (threadIdx.x == 0)
        atomicAdd(out, red[0] + red[1] + red[2] + red[3]);
}

// ---------------------------------------------------------------------------
extern "C" void kernel_launch(void* const* d_in, const int* in_sizes, int n_in,
                              void* d_out, int out_size, void* d_ws, size_t ws_size,
                              hipStream_t stream)
{
    const float* img = (const float*)d_in[0];
    const float* txt = (const float*)d_in[1];

    char* ws = (char*)d_ws;
    __hip_bfloat16* imgB = (__hip_bfloat16*)(ws);                        // 1 MB
    __hip_bfloat16* txtB = (__hip_bfloat16*)(ws + (1u << 20));           // 1 MB
    float* diag   = (float*)(ws + (2u << 20));                           // 32 KB
    float* rowSum = (float*)(ws + (2u << 20) + (1u << 15));              // 32 KB
    float* colSum = (float*)(ws + (2u << 20) + (2u << 15));              // 32 KB

    norm_kernel<<<512, 256, 0, stream>>>(img, txt, imgB, txtB, diag, rowSum, colSum, (float*)d_out);
    score_kernel<<<1024, 256, 0, stream>>>(imgB, txtB, rowSum, colSum);
    finish_kernel<<<NB / 256, 256, 0, stream>>>(rowSum, colSum, diag, (float*)d_out);
}